// Round 3
// baseline (45181.726 us; speedup 1.0000x reference)
//
#include <hip/hip_runtime.h>
#include <math.h>

#define DEV_INLINE __device__ __forceinline__

static constexpr int Bn = 64;     // batch
static constexpr int Tn = 512;    // time
static constexpr int En = 512;    // embed
static constexpr int Hn = 1024;   // hidden
static constexpr int Cn = 256;    // classes
static constexpr int Gn = 4 * Hn; // 4096 gates

typedef float v4f __attribute__((ext_vector_type(4)));

DEV_INLINE float sigmoidf_(float v) { return 1.f / (1.f + __expf(-v)); }

// ---------------------------------------------------------------------------
// Generic fp32 tiled GEMM:  C[M,N] = A[M,K] * B[N,K]^T + bias1[n] (+bias2[n])
// ---------------------------------------------------------------------------
__global__ __launch_bounds__(256) void gemm_tt(
    const float* __restrict__ A, const float* __restrict__ Bm,
    const float* __restrict__ bias1, const float* __restrict__ bias2,
    float* __restrict__ Cm, int M, int N, int K)
{
  constexpr int KC = 32;
  __shared__ float As[KC][68];
  __shared__ float Bs[KC][68];
  const int tid = threadIdx.x;
  const int tx = tid & 15, ty = tid >> 4;
  const int m0 = blockIdx.x * 64, n0 = blockIdx.y * 64;

  float acc[4][4] = {};

  for (int k0 = 0; k0 < K; k0 += KC) {
    __syncthreads();
    #pragma unroll
    for (int j = 0; j < 2; ++j) {
      int f = tid + j * 256;
      int row = f >> 3;
      int c4 = f & 7;
      float4 va = *reinterpret_cast<const float4*>(&A[(size_t)(m0 + row) * K + k0 + c4 * 4]);
      As[c4 * 4 + 0][row] = va.x; As[c4 * 4 + 1][row] = va.y;
      As[c4 * 4 + 2][row] = va.z; As[c4 * 4 + 3][row] = va.w;
      float4 vb = *reinterpret_cast<const float4*>(&Bm[(size_t)(n0 + row) * K + k0 + c4 * 4]);
      Bs[c4 * 4 + 0][row] = vb.x; Bs[c4 * 4 + 1][row] = vb.y;
      Bs[c4 * 4 + 2][row] = vb.z; Bs[c4 * 4 + 3][row] = vb.w;
    }
    __syncthreads();
    #pragma unroll
    for (int k = 0; k < KC; ++k) {
      float4 a4 = *reinterpret_cast<const float4*>(&As[k][ty * 4]);
      float4 b4 = *reinterpret_cast<const float4*>(&Bs[k][tx * 4]);
      float ar[4] = {a4.x, a4.y, a4.z, a4.w};
      float br[4] = {b4.x, b4.y, b4.z, b4.w};
      #pragma unroll
      for (int i = 0; i < 4; ++i)
        #pragma unroll
        for (int j = 0; j < 4; ++j)
          acc[i][j] += ar[i] * br[j];
    }
  }

  #pragma unroll
  for (int j = 0; j < 4; ++j) {
    int n = n0 + tx * 4 + j;
    float bb = bias1[n];
    if (bias2) bb += bias2[n];
    #pragma unroll
    for (int i = 0; i < 4; ++i)
      Cm[(size_t)(m0 + ty * 4 + i) * N + n] = acc[i][j] + bb;
  }
}

// ---------------------------------------------------------------------------
// W-stationary persistent LSTM. 256 blocks x 512 threads (1 block/CU).
// Block (bg 0..3, hg 0..63): batch rows [bg*16,+16), h-cols [hg*16,+16).
// W held in registers (wv[4][8] float4 = 128 VGPR) for the whole kernel.
// Per step: stage h[t-1] tile (64KB) via 16B coherent (sc0 sc1) loads -> LDS,
// 2048 reg-resident FMAs, log2(32) reduce-scatter, elementwise, 16B coherent
// h store via LDS repack, 2-level tree barrier (1 poller/block, s_sleep).
// ---------------------------------------------------------------------------

#define FG_(b,g,j,H) a[(g)*16+(b)] = __builtin_fmaf((H).w, wv[g][j].w, \
    __builtin_fmaf((H).z, wv[g][j].z, __builtin_fmaf((H).y, wv[g][j].y, \
    __builtin_fmaf((H).x, wv[g][j].x, a[(g)*16+(b)]))));
#define JS_(b,j) { v4f Hv = hsm4[(b)*256 + jidx[j]]; \
  FG_(b,0,j,Hv) FG_(b,1,j,Hv) FG_(b,2,j,Hv) FG_(b,3,j,Hv) }
#define ROW_(b) JS_(b,0) JS_(b,1) JS_(b,2) JS_(b,3) JS_(b,4) JS_(b,5) JS_(b,6) JS_(b,7)
#define KLOOP ROW_(0) ROW_(1) ROW_(2) ROW_(3) ROW_(4) ROW_(5) ROW_(6) ROW_(7) \
              ROW_(8) ROW_(9) ROW_(10) ROW_(11) ROW_(12) ROW_(13) ROW_(14) ROW_(15)

#define RROUND(L, MASK, BIT) \
  _Pragma("unroll") \
  for (int j2 = 0; j2 < (L); ++j2) { \
    float snd = (BIT) ? a[j2] : a[j2 + (L)]; \
    float kp  = (BIT) ? a[j2 + (L)] : a[j2]; \
    a[j2] = kp + __shfl_xor(snd, (MASK)); \
  }

__global__ __launch_bounds__(512, 2) void lstm_persistent(
    const int* __restrict__ x,        // [B, T]
    const float* __restrict__ Whh,    // [4H, H]
    const float* __restrict__ proj,   // [C, 4H] class gates incl. both biases
    float* __restrict__ hs,           // [B, T, H]
    int* __restrict__ flags)          // tree barrier state
{
  __shared__ __align__(16) float hsm[16 * 1024];   // 64 KB staged h tile
  float* gbufF  = hsm;          // gate exchange buffer aliases rows 0..1023
  float* hstage = hsm + 1024;   // h repack buffer aliases row-1 region

  const int tid = threadIdx.x;
  const int bid = blockIdx.x;
  const int bg = bid >> 6;       // 0..3
  const int hg = bid & 63;       // 0..63
  const int b0 = bg * 16;

  const int w_ = tid >> 6;       // wave 0..7
  const int lane = tid & 63;
  const int hcm = lane & 1;
  const int ks = lane >> 1;      // 0..31 K-split
  const int hc_l = w_ * 2 + hcm; // 0..15
  const int hc = hg * 16 + hc_l;

  // ---- one-time W preload into registers (read order rotated by ks)
  v4f wv[4][8];
  #pragma unroll
  for (int g = 0; g < 4; ++g) {
    const float* wb = Whh + ((size_t)(g * 1024 + hc)) * 1024 + ks * 32;
    #pragma unroll
    for (int j = 0; j < 8; ++j)
      wv[g][j] = *(const v4f*)(wb + ((ks + j) & 7) * 4);
  }
  int jidx[8];
  #pragma unroll
  for (int j = 0; j < 8; ++j) jidx[j] = ks * 8 + ((ks + j) & 7);

  v4f* hsm4 = (v4f*)hsm;

  const int ew = (tid < 256);
  const int b_l = tid >> 4, hcl = tid & 15;        // elementwise mapping
  const int* xp = x + (size_t)(b0 + b_l) * Tn;
  float cst = 0.f;

  // ---- tree barrier pointers (per group: 8 L0 + 1 L1 + 1 GEN, 128B lines)
  int* L0  = flags + (size_t)(bg * 10 + (hg >> 3)) * 32;
  int* L1  = flags + (size_t)(bg * 10 + 8) * 32;
  int* GEN = flags + (size_t)(bg * 10 + 9) * 32;

  // final element ids after reduce-scatter (bit-reversed ks)
  const int e0 = ((ks & 1) << 5) | (((ks >> 1) & 1) << 4) | (((ks >> 2) & 1) << 3)
               | (((ks >> 3) & 1) << 2) | (((ks >> 4) & 1) << 1);
  const int e1 = e0 | 1;

  const int c4 = tid & 255;      // staging column (float4 granularity)
  const int rb = tid >> 8;       // staging row base 0/1

  for (int t = 0; t < Tn; ++t) {
    // class projection prefetch (independent of h; overlaps staging)
    float p0 = 0.f, p1 = 0.f, p2 = 0.f, p3 = 0.f;
    if (ew) {
      int cls = xp[t];
      const float* pb = proj + (size_t)cls * Gn + hg * 16 + hcl;
      p0 = pb[0]; p1 = pb[Hn]; p2 = pb[2 * Hn]; p3 = pb[3 * Hn];
    }

    if (t > 0) {
      // stage h[t-1]: 8x 16B cross-XCD-coherent loads per thread
      const float* ap[8];
      #pragma unroll
      for (int l = 0; l < 8; ++l)
        ap[l] = hs + ((size_t)(b0 + rb + 2 * l) * Tn + (t - 1)) * Hn + c4 * 4;
      v4f r0, r1, r2, r3, r4, r5, r6, r7;
      asm volatile(
        "global_load_dwordx4 %0, %8, off sc0 sc1\n\t"
        "global_load_dwordx4 %1, %9, off sc0 sc1\n\t"
        "global_load_dwordx4 %2, %10, off sc0 sc1\n\t"
        "global_load_dwordx4 %3, %11, off sc0 sc1\n\t"
        "global_load_dwordx4 %4, %12, off sc0 sc1\n\t"
        "global_load_dwordx4 %5, %13, off sc0 sc1\n\t"
        "global_load_dwordx4 %6, %14, off sc0 sc1\n\t"
        "global_load_dwordx4 %7, %15, off sc0 sc1\n\t"
        "s_waitcnt vmcnt(0)"
        : "=&v"(r0), "=&v"(r1), "=&v"(r2), "=&v"(r3),
          "=&v"(r4), "=&v"(r5), "=&v"(r6), "=&v"(r7)
        : "v"(ap[0]), "v"(ap[1]), "v"(ap[2]), "v"(ap[3]),
          "v"(ap[4]), "v"(ap[5]), "v"(ap[6]), "v"(ap[7])
        : "memory");
      hsm4[tid +    0] = r0;  hsm4[tid +  512] = r1;
      hsm4[tid + 1024] = r2;  hsm4[tid + 1536] = r3;
      hsm4[tid + 2048] = r4;  hsm4[tid + 2560] = r5;
      hsm4[tid + 3072] = r6;  hsm4[tid + 3584] = r7;
    }
    __syncthreads();

    float a[64];
    #pragma unroll
    for (int i = 0; i < 64; ++i) a[i] = 0.f;

    if (t > 0) { KLOOP }

    // reduce-scatter over the 32 ks lanes: 62 shuffles total
    RROUND(32, 2, (ks & 1))
    RROUND(16, 4, ((ks >> 1) & 1))
    RROUND(8, 8, ((ks >> 2) & 1))
    RROUND(4, 16, ((ks >> 3) & 1))
    RROUND(2, 32, ((ks >> 4) & 1))

    __syncthreads();   // hsm KLOOP reads done before gbuf (aliased) writes
    gbufF[(e0 & 15) * 64 + (e0 >> 4) * 16 + hc_l] = a[0];
    gbufF[(e1 & 15) * 64 + (e1 >> 4) * 16 + hc_l] = a[1];
    __syncthreads();

    if (ew) {
      float g0 = gbufF[b_l * 64 +  0 + hcl] + p0;
      float g1 = gbufF[b_l * 64 + 16 + hcl] + p1;
      float g2 = gbufF[b_l * 64 + 32 + hcl] + p2;
      float g3 = gbufF[b_l * 64 + 48 + hcl] + p3;
      float ig = sigmoidf_(g0), fg = sigmoidf_(g1);
      float gg = tanhf(g2),     og = sigmoidf_(g3);
      cst = fg * cst + ig * gg;
      hstage[tid] = og * tanhf(cst);
    }
    __syncthreads();

    if (tid < 64) {
      // repack to 16B coherent stores: 4 threads cover one batch row
      float* sp = hs + ((size_t)(b0 + (tid >> 2)) * Tn + t) * Hn
                     + hg * 16 + (tid & 3) * 4;
      v4f v = *(const v4f*)&hstage[tid * 4];
      asm volatile(
        "global_store_dwordx4 %0, %1, off sc0 sc1\n\t"
        "s_waitcnt vmcnt(0)"
        :: "v"(sp), "v"(v) : "memory");
    }

    if (t + 1 < Tn) {
      __syncthreads();   // all h stores drained before arrival
      if (tid == 0) {
        int target = 8 * (t + 1);
        int old = __hip_atomic_fetch_add(L0, 1, __ATOMIC_RELAXED,
                                         __HIP_MEMORY_SCOPE_AGENT);
        if (old == target - 1) {
          int o1 = __hip_atomic_fetch_add(L1, 1, __ATOMIC_RELAXED,
                                          __HIP_MEMORY_SCOPE_AGENT);
          if (o1 == target - 1)
            __hip_atomic_store(GEN, t + 1, __ATOMIC_RELAXED,
                               __HIP_MEMORY_SCOPE_AGENT);
        }
        while (__hip_atomic_load(GEN, __ATOMIC_RELAXED,
                                 __HIP_MEMORY_SCOPE_AGENT) < t + 1)
          __builtin_amdgcn_s_sleep(8);
      }
      __syncthreads();
    }
  }
}

// ---------------------------------------------------------------------------
extern "C" void kernel_launch(void* const* d_in, const int* in_sizes, int n_in,
                              void* d_out, int out_size, void* d_ws, size_t ws_size,
                              hipStream_t stream) {
  const int*   x     = (const int*)  d_in[0];
  const float* embed = (const float*)d_in[1];
  const float* Wih   = (const float*)d_in[2];
  const float* Whh   = (const float*)d_in[3];
  const float* bih   = (const float*)d_in[4];
  const float* bhh   = (const float*)d_in[5];
  const float* fcW   = (const float*)d_in[6];
  const float* fcb   = (const float*)d_in[7];
  float* out = (float*)d_out;

  char* ws = (char*)d_ws;
  const size_t flagBytes = 32768;
  const size_t projBytes = (size_t)Cn * Gn * sizeof(float);          // 4 MB
  const size_t hsBytes   = (size_t)Bn * Tn * Hn * sizeof(float);     // 128 MB
  const size_t need = flagBytes + projBytes + hsBytes;
  if (ws_size < need) {
    hipMemsetAsync(d_out, 0, (size_t)out_size * sizeof(float), stream);
    return;
  }
  float* proj = (float*)(ws + flagBytes);
  float* hs   = (float*)(ws + flagBytes + projBytes);

  // zero barrier flags every call (graph-capture-safe async memset)
  hipMemsetAsync(d_ws, 0, flagBytes, stream);

  // 1) proj[cls, 4H] = embed[cls,:] @ W_ih^T + b_ih + b_hh
  dim3 g1(Cn / 64, Gn / 64);   // (4, 64)
  gemm_tt<<<g1, 256, 0, stream>>>(embed, Wih, bih, bhh, proj, Cn, Gn, En);

  // 2) W-stationary persistent recurrence
  lstm_persistent<<<256, 512, 0, stream>>>(x, Whh, proj, hs, (int*)d_ws);

  // 3) out[b*T+t, c] = hs[b,t,:] @ fc_W^T + fc_b
  dim3 g3((Bn * Tn) / 64, Cn / 64);  // (512, 4)
  gemm_tt<<<g3, 256, 0, stream>>>(hs, fcW, fcb, nullptr, out, Bn * Tn, Cn, Hn);
}